// Round 4
// baseline (365.272 us; speedup 1.0000x reference)
//
#include <hip/hip_runtime.h>

// relu(x @ W^T + b): M=131072, K=256, N=256, f32 in/out.
// R4: guaranteed-correct fp32 VALU SGEMM (no MFMA). Three MFMA rounds
// produced value-corruption (absmax 5.66 > 3.5 placement-error bound,
// act std ~1.0 vs correct 0.577) that layout algebra + self-calibration
// could not explain. This round secures a passing baseline + counters;
// MFMA gets re-introduced later via slice-A/B against this known-good path.
//
// Structure: 128x128 block tile, 8x8 per-thread micro-tile, BK=32 K-chunks
// staged in LDS (f32, +4 pad to break bank conflicts on the x side),
// float4 LDS reads, fused bias+ReLU epilogue.

#define BM 128
#define BN 128
#define BK 32
#define PAD 4

__global__ __launch_bounds__(256)
void gemm_valu_kernel(const float* __restrict__ x,
                      const float* __restrict__ W,
                      const float* __restrict__ bias,
                      float* __restrict__ out) {
    __shared__ float xs[BK][BM + PAD];   // xs[k][m] = x[row0+m][kc+k]
    __shared__ float ws[BK][BN + PAD];   // ws[k][n] = W[col0+n][kc+k]

    const int tid = threadIdx.x;         // 0..255
    const int tx  = tid & 15;            // col group (8 cols each)
    const int ty  = tid >> 4;            // row group (8 rows each)
    const int rt  = (int)(blockIdx.x >> 1);
    const int ct  = (int)(blockIdx.x & 1);
    const long row0 = (long)rt * BM;
    const int  col0 = ct * BN;

    const int kq = tid & 7;              // float4 position along k
    const int rr = tid >> 3;             // 0..31: row/col index for staging

    float acc[8][8];
#pragma unroll
    for (int i = 0; i < 8; ++i)
#pragma unroll
        for (int j = 0; j < 8; ++j) acc[i][j] = 0.f;

    for (int kc = 0; kc < 256; kc += BK) {
        // Stage x-tile and W-tile: each thread moves 4 float4 of each.
#pragma unroll
        for (int rep = 0; rep < 4; ++rep) {
            int r = rr + rep * 32;       // 0..127
            float4 v = *(const float4*)(x + (row0 + r) * 256 + kc + kq * 4);
            xs[kq * 4 + 0][r] = v.x; xs[kq * 4 + 1][r] = v.y;
            xs[kq * 4 + 2][r] = v.z; xs[kq * 4 + 3][r] = v.w;
            float4 u = *(const float4*)(W + (long)(col0 + r) * 256 + kc + kq * 4);
            ws[kq * 4 + 0][r] = u.x; ws[kq * 4 + 1][r] = u.y;
            ws[kq * 4 + 2][r] = u.z; ws[kq * 4 + 3][r] = u.w;
        }
        __syncthreads();

#pragma unroll
        for (int k = 0; k < BK; ++k) {
            float xr[8], wr[8];
            *(float4*)&xr[0] = *(const float4*)&xs[k][ty * 8];
            *(float4*)&xr[4] = *(const float4*)&xs[k][ty * 8 + 4];
            *(float4*)&wr[0] = *(const float4*)&ws[k][tx * 8];
            *(float4*)&wr[4] = *(const float4*)&ws[k][tx * 8 + 4];
#pragma unroll
            for (int i = 0; i < 8; ++i)
#pragma unroll
                for (int j = 0; j < 8; ++j)
                    acc[i][j] += xr[i] * wr[j];
        }
        __syncthreads();
    }

    // Epilogue: bias + ReLU, float4 stores.
#pragma unroll
    for (int i = 0; i < 8; ++i) {
        long row = row0 + ty * 8 + i;
#pragma unroll
        for (int jq = 0; jq < 2; ++jq) {
            float4 o;
            float* po = (float*)&o;
#pragma unroll
            for (int j = 0; j < 4; ++j) {
                int col = col0 + tx * 8 + jq * 4 + j;
                float v = acc[i][jq * 4 + j] + bias[col];
                po[j] = v > 0.f ? v : 0.f;
            }
            *(float4*)(out + row * 256 + col0 + tx * 8 + jq * 4) = o;
        }
    }
}

extern "C" void kernel_launch(void* const* d_in, const int* in_sizes, int n_in,
                              void* d_out, int out_size, void* d_ws, size_t ws_size,
                              hipStream_t stream) {
    (void)n_in; (void)d_ws; (void)ws_size; (void)out_size;
    const float* x = (const float*)d_in[0];
    const float* W = (const float*)d_in[1];
    const float* b = (const float*)d_in[2];
    float* out = (float*)d_out;

    const int M = in_sizes[0] / 256;     // 131072
    const int grid = (M / BM) * 2;       // 1024 row-tiles x 2 col-tiles = 2048

    gemm_valu_kernel<<<grid, 256, 0, stream>>>(x, W, b, out);
}